// Round 1
// baseline (1078.146 us; speedup 1.0000x reference)
//
#include <hip/hip_runtime.h>
#include <cstdint>
#include <cstddef>

// GAT forward: query = ufea@W^T + b; S = leaky2((q@inter^T)/sqrt(D)) masked by adj;
// out = softmax(S) @ inter.   N=10000 users, M=12000 items, D=128.
// Strategy: bf16 MFMA flash-style single pass (no max subtraction needed: |scores|<~6).
// adj (480MB) is the HBM floor (~76us); inter/q stay L2-resident (bf16 copies, ~6MB).

#define N_USERS 10000
#define N_ITEMS 12000
#define HD      128
#define QROWS   10048      // 157*64 padded user rows
#define NCHUNK  8
#define NTILES  188        // ceil(12000/64); tile 187 has 32 valid items
#define UBLOCKS 157
#define KT_PITCH 12032     // interT row pitch (pad so tail-tile reads stay in-buffer)

typedef __bf16 bf16x8 __attribute__((ext_vector_type(8)));
typedef __bf16 bf16x4 __attribute__((ext_vector_type(4)));
typedef float  f32x4  __attribute__((ext_vector_type(4)));

// ---------------- inter -> bf16 (row-major) + bf16 transposed copy ----------------
__global__ __launch_bounds__(256) void cast_inter_kernel(const float* __restrict__ inter,
                                                         __bf16* __restrict__ kg,
                                                         __bf16* __restrict__ ktg) {
    __shared__ __bf16 Tl[128 * 72];   // [d][item_local], pitch 72 (16B-aligned rows)
    const int t  = threadIdx.x;
    const int i0 = blockIdx.x * 64;
    for (int it = 0; it < 8; ++it) {
        int g   = it * 256 + t;
        int row = g >> 5;            // 0..63 item_local
        int d   = (g & 31) * 4;      // 0..124
        int item = i0 + row;
        if (item < N_ITEMS) {
            f32x4 v = *(const f32x4*)(inter + (size_t)item * HD + d);
            __bf16 b0 = (__bf16)v.x, b1 = (__bf16)v.y, b2 = (__bf16)v.z, b3 = (__bf16)v.w;
            bf16x4 pk = {b0, b1, b2, b3};
            *(bf16x4*)(kg + (size_t)item * HD + d) = pk;
            Tl[(d + 0) * 72 + row] = b0;
            Tl[(d + 1) * 72 + row] = b1;
            Tl[(d + 2) * 72 + row] = b2;
            Tl[(d + 3) * 72 + row] = b3;
        } else {
            Tl[(d + 0) * 72 + row] = (__bf16)0.f;
            Tl[(d + 1) * 72 + row] = (__bf16)0.f;
            Tl[(d + 2) * 72 + row] = (__bf16)0.f;
            Tl[(d + 3) * 72 + row] = (__bf16)0.f;
        }
    }
    __syncthreads();
    const int d  = t >> 1;
    const int jb = (t & 1) * 32;
    if (i0 + jb < N_ITEMS) {          // 12000 % 32 == 0 so validity is per-half
        #pragma unroll
        for (int k = 0; k < 4; ++k) {
            bf16x8 v = *(const bf16x8*)&Tl[d * 72 + jb + k * 8];
            *(bf16x8*)(ktg + (size_t)d * KT_PITCH + i0 + jb + k * 8) = v;
        }
    }
}

// ---------------- query = ufea @ W^T + b  (bf16 MFMA, output bf16) ----------------
__global__ __launch_bounds__(256) void query_kernel(const float* __restrict__ ufea,
                                                    const float* __restrict__ W,
                                                    const float* __restrict__ bias,
                                                    __bf16* __restrict__ qg) {
    const int lane = threadIdx.x & 63, wave = threadIdx.x >> 6;
    const int n = lane & 15, qd = lane >> 4;
    const int user0 = blockIdx.x * 64 + wave * 16;
    int arow = user0 + n; if (arow > N_USERS - 1) arow = N_USERS - 1;

    bf16x8 af[4];
    #pragma unroll
    for (int kk = 0; kk < 4; ++kk) {
        const float* p = ufea + (size_t)arow * HD + kk * 32 + qd * 8;
        f32x4 lo = *(const f32x4*)p, hi = *(const f32x4*)(p + 4);
        bf16x8 a;
        a[0]=(__bf16)lo.x; a[1]=(__bf16)lo.y; a[2]=(__bf16)lo.z; a[3]=(__bf16)lo.w;
        a[4]=(__bf16)hi.x; a[5]=(__bf16)hi.y; a[6]=(__bf16)hi.z; a[7]=(__bf16)hi.w;
        af[kk] = a;
    }
    #pragma unroll
    for (int nt = 0; nt < 8; ++nt) {
        f32x4 acc = {0.f, 0.f, 0.f, 0.f};
        #pragma unroll
        for (int kk = 0; kk < 4; ++kk) {
            const float* p = W + (size_t)(nt * 16 + n) * HD + kk * 32 + qd * 8;
            f32x4 lo = *(const f32x4*)p, hi = *(const f32x4*)(p + 4);
            bf16x8 b;
            b[0]=(__bf16)lo.x; b[1]=(__bf16)lo.y; b[2]=(__bf16)lo.z; b[3]=(__bf16)lo.w;
            b[4]=(__bf16)hi.x; b[5]=(__bf16)hi.y; b[6]=(__bf16)hi.z; b[7]=(__bf16)hi.w;
            acc = __builtin_amdgcn_mfma_f32_16x16x32_bf16(af[kk], b, acc, 0, 0, 0);
        }
        const float bv = bias[nt * 16 + n];
        #pragma unroll
        for (int r = 0; r < 4; ++r) {
            int row = user0 + qd * 4 + r;   // always < QROWS; pad rows hold clamped dup (unused)
            qg[(size_t)row * HD + nt * 16 + n] = (__bf16)(acc[r] + bv);
        }
    }
}

// ---------------- fused: S = q@k^T, mask+leaky+exp, O += P@V, l += rowsum ----------------
__global__ __launch_bounds__(256) void fused_kernel(const __bf16* __restrict__ qg,
                                                    const __bf16* __restrict__ kg,
                                                    const __bf16* __restrict__ ktg,
                                                    const int* __restrict__ adj,
                                                    float* __restrict__ Opart,
                                                    float* __restrict__ lpart) {
    __shared__ __bf16 Pl[4][16 * 72];   // per-wave P buffer, row pitch 72
    const int lane = threadIdx.x & 63, wave = threadIdx.x >> 6;
    const int n = lane & 15, qd = lane >> 4;
    const int user0 = blockIdx.x * 64 + wave * 16;
    const int chunk = blockIdx.y;
    const int t0 = (chunk * NTILES) / NCHUNK;
    const int t1 = ((chunk + 1) * NTILES) / NCHUNK;
    const float SC = (float)(1.4426950408889634 * 0.08838834764831845); // log2(e)/sqrt(128)

    bf16x8 qf[4];
    #pragma unroll
    for (int kk = 0; kk < 4; ++kk)
        qf[kk] = *(const bf16x8*)(qg + (size_t)(user0 + n) * HD + kk * 32 + qd * 8);

    f32x4 Oacc[8];
    #pragma unroll
    for (int dt = 0; dt < 8; ++dt) Oacc[dt] = (f32x4){0.f, 0.f, 0.f, 0.f};
    float lacc[4] = {0.f, 0.f, 0.f, 0.f};

    int rowc[4];
    #pragma unroll
    for (int r = 0; r < 4; ++r) {
        int u = user0 + qd * 4 + r;
        rowc[r] = (u > N_USERS - 1) ? (N_USERS - 1) : u;
    }
    __bf16* pw = &Pl[wave][0];

    for (int t = t0; t < t1; ++t) {
        const int j0 = t * 64;
        f32x4 S[4];
        #pragma unroll
        for (int nt = 0; nt < 4; ++nt) S[nt] = (f32x4){0.f, 0.f, 0.f, 0.f};
        #pragma unroll
        for (int nt = 0; nt < 4; ++nt) {
            int krow = j0 + nt * 16 + n; if (krow > N_ITEMS - 1) krow = N_ITEMS - 1;
            const __bf16* kp = kg + (size_t)krow * HD + qd * 8;
            #pragma unroll
            for (int kk = 0; kk < 4; ++kk) {
                bf16x8 b = *(const bf16x8*)(kp + kk * 32);
                S[nt] = __builtin_amdgcn_mfma_f32_16x16x32_bf16(qf[kk], b, S[nt], 0, 0, 0);
            }
        }
        // mask + leaky2 + exp2 -> P (bf16 in LDS), l accumulation
        #pragma unroll
        for (int nt = 0; nt < 4; ++nt) {
            const int col = j0 + nt * 16 + n;
            const bool cv = col < N_ITEMS;
            const int colc = cv ? col : N_ITEMS - 1;
            #pragma unroll
            for (int r = 0; r < 4; ++r) {
                int a = __builtin_nontemporal_load(adj + (size_t)rowc[r] * N_ITEMS + colc);
                float s = S[nt][r] * SC;
                s = fminf(s, s + s);                      // leaky_relu(slope 2), pre-scaled
                float p = (cv && a > 0) ? __builtin_amdgcn_exp2f(s) : 0.f;
                lacc[r] += p;
                pw[(qd * 4 + r) * 72 + nt * 16 + n] = (__bf16)p;
            }
        }
        __syncthreads();   // P C-layout -> A-layout round trip (intra-wave, fence for ordering)
        #pragma unroll
        for (int kc = 0; kc < 2; ++kc) {
            bf16x8 af = *(const bf16x8*)(pw + n * 72 + kc * 32 + qd * 8);
            #pragma unroll
            for (int dt = 0; dt < 8; ++dt) {
                bf16x8 b = *(const bf16x8*)(ktg + (size_t)(dt * 16 + n) * KT_PITCH + j0 + kc * 32 + qd * 8);
                Oacc[dt] = __builtin_amdgcn_mfma_f32_16x16x32_bf16(af, b, Oacc[dt], 0, 0, 0);
            }
        }
        __syncthreads();
    }

    // reduce l across the 16 lanes of each quad (each lane covered cols == n mod 16)
    #pragma unroll
    for (int r = 0; r < 4; ++r) {
        float v = lacc[r];
        v += __shfl_xor(v, 1);
        v += __shfl_xor(v, 2);
        v += __shfl_xor(v, 4);
        v += __shfl_xor(v, 8);
        lacc[r] = v;
    }
    const size_t cb = (size_t)chunk * QROWS;
    #pragma unroll
    for (int r = 0; r < 4; ++r) {
        const int user = user0 + qd * 4 + r;
        if (user < N_USERS) {
            #pragma unroll
            for (int dt = 0; dt < 8; ++dt)
                Opart[(cb + user) * HD + dt * 16 + n] = Oacc[dt][r];
            if (n == 0) lpart[cb + user] = lacc[r];
        }
    }
}

// ---------------- combine partials: out = (sum_c O_c) / (sum_c l_c) ----------------
__global__ __launch_bounds__(256) void combine_kernel(const float* __restrict__ Opart,
                                                      const float* __restrict__ lpart,
                                                      float* __restrict__ out) {
    const int g = blockIdx.x * 256 + threadIdx.x;   // 320000 threads exactly
    const int base = g * 4;
    const int user = base >> 7;
    const int d = base & 127;
    f32x4 acc = {0.f, 0.f, 0.f, 0.f};
    float l = 0.f;
    #pragma unroll
    for (int c = 0; c < NCHUNK; ++c) {
        acc += *(const f32x4*)(Opart + ((size_t)c * QROWS + user) * HD + d);
        l += lpart[(size_t)c * QROWS + user];
    }
    f32x4 res = acc / l;
    *(f32x4*)(out + (size_t)user * HD + d) = res;
}

extern "C" void kernel_launch(void* const* d_in, const int* in_sizes, int n_in,
                              void* d_out, int out_size, void* d_ws, size_t ws_size,
                              hipStream_t stream) {
    const float* ufea = (const float*)d_in[0];
    const float* inter = (const float*)d_in[1];
    const int*   adj  = (const int*)d_in[2];
    const float* W    = (const float*)d_in[3];
    const float* bias = (const float*)d_in[4];
    float* out = (float*)d_out;

    char* ws = (char*)d_ws;
    // layout (bytes, all 256-aligned):
    //   qg    : 10048*128*2      = 2,572,288
    //   kg    : 12000*128*2      = 3,072,000
    //   ktg   : 128*12032*2      = 3,080,192
    //   Opart : 8*10048*128*4    = 41,156,608
    //   lpart : 8*10048*4        = 321,536          total ~50.2 MB
    __bf16* qg   = (__bf16*)(ws);
    __bf16* kg   = (__bf16*)(ws + 2572288);
    __bf16* ktg  = (__bf16*)(ws + 2572288 + 3072000);
    float*  Opart = (float*)(ws + 2572288 + 3072000 + 3080192);
    float*  lpart = (float*)(ws + 2572288 + 3072000 + 3080192 + 41156608);

    cast_inter_kernel<<<dim3(188), dim3(256), 0, stream>>>(inter, kg, ktg);
    query_kernel<<<dim3(UBLOCKS), dim3(256), 0, stream>>>(ufea, W, bias, qg);
    fused_kernel<<<dim3(UBLOCKS, NCHUNK), dim3(256), 0, stream>>>(qg, kg, ktg, adj, Opart, lpart);
    combine_kernel<<<dim3(1250), dim3(256), 0, stream>>>(Opart, lpart, out);
}